// Round 11
// baseline (95.310 us; speedup 1.0000x reference)
//
#include <hip/hip_runtime.h>
#include <hip/hip_bf16.h>
#include <stdint.h>
#include <stddef.h>

// ---------------------------------------------------------------------------
// MyConv2D fixed-point conv (Width=8), valid 3x3, NHWC, + bias + ReLU.
// R11: R10's barrier-free K-loop with the footprint bug fixed.
//   R10 bug: 128-m blocks with (m0i%54)>=35 span 4 output rows -> need 6
//   input rows; only 5 were staged. Fix: block = 128 m x ALL 256 f
//   (512 thr, 8 waves 2Mx4N, 64x64/wave) and stage 6 input rows (84 KB LDS,
//   always sufficient: (s+127)/54 < 4 for s<=53). 1 block/CU, 8 waves.
// Structure: x footprint staged ONCE (global_load_lds w16, source
// pre-swizzled cc^(w&7)); K-loop = 9 taps x 4 ks = 36 steps, 576 MFMA/wave,
// ZERO barriers after the single staging barrier. A = ds_read_b128 from
// resident x tile (read-side XOR matches staging swizzle); B = global->VGPR
// fragment-order (proven R6-R9), 3-set rotation prefetched 2 steps ahead.
// Grid 736 = 8*92: XCD-chunked, 4 images/XCD -> x L2-resident.
// Exactness: quantized values a/256, |a|<=256 (bf16-exact); partial sums are
// integer multiples of 2^-16 << 2^24 -> fp32 MFMA accumulation exact.
// ---------------------------------------------------------------------------

typedef float  f32x4  __attribute__((ext_vector_type(4)));
typedef short  bf16x8 __attribute__((ext_vector_type(8)));

#define N_IMG 32
#define H_IN 56
#define W_IN 56
#define C_IN 128
#define F_OUT 256
#define OHW 54
#define RPI 2916                       // rows per image = 54*54
#define BPI 23                         // ceil(2916/128) blocks per image
#define BM 128
#define ROW_SHORTS (W_IN * C_IN)       // 7168 shorts = 14336 B per input row
#define NWG (N_IMG * BPI)              // 736 = 8 * 92

__device__ __forceinline__ unsigned short quant_to_bf16(float x) {
    float a = rintf(x * 256.0f);                 // half-to-even == jnp.round
    a = fminf(fmaxf(a, -256.0f), 256.0f);
    float q = a * 0.00390625f;                   // exact in bf16
    union { float f; unsigned int u; } cv; cv.f = q;
    return (unsigned short)(cv.u >> 16);
}

__device__ __forceinline__ void async_copy16(const unsigned short* g, unsigned short* l) {
    __builtin_amdgcn_global_load_lds(
        (const __attribute__((address_space(1))) unsigned int*)g,
        (__attribute__((address_space(3))) unsigned int*)l, 16, 0, 0);
}

__global__ __launch_bounds__(256) void quant_x_kernel(
        const float* __restrict__ x, unsigned short* __restrict__ xq) {
    int i = (blockIdx.x * 256 + threadIdx.x) * 4;
    float4 v = *reinterpret_cast<const float4*>(x + i);
    ushort4 o;
    o.x = quant_to_bf16(v.x);
    o.y = quant_to_bf16(v.y);
    o.z = quant_to_bf16(v.z);
    o.w = quant_to_bf16(v.w);
    *reinterpret_cast<ushort4*>(xq + i) = o;
}

// w (3,3,128,256) -> wpf in MFMA-B fragment order, one 32-K group per step:
//   idx = (((kk*4 + ks)*16 + g)*64 + l)*8 + j
//   element: f = g*16 + (l&15); c = ks*32 + (l>>4)*8 + j; tap kk
__global__ __launch_bounds__(256) void quant_w_kernel(
        const float* __restrict__ w, unsigned short* __restrict__ wpf) {
    int idx = blockIdx.x * 256 + threadIdx.x;     // 294912 total
    int j  = idx & 7;
    int l  = (idx >> 3) & 63;
    int g  = (idx >> 9) & 15;
    int ks = (idx >> 13) & 3;
    int kk = idx >> 15;
    int f  = g * 16 + (l & 15);
    int c  = ks * 32 + (l >> 4) * 8 + j;
    wpf[idx] = quant_to_bf16(w[(kk * C_IN + c) * F_OUT + f]);
}

__global__ __launch_bounds__(512, 1) void conv_kernel(
        const unsigned short* __restrict__ xq,   // [32][56][56][128] bf16
        const unsigned short* __restrict__ wpf,  // fragment-ordered B
        const float* __restrict__ bias,          // [54][54][256]
        float* __restrict__ out)                 // [93312][256]
{
    __shared__ __attribute__((aligned(16))) unsigned short Xlds[6 * ROW_SHORTS]; // 86016 B

    const int tid  = threadIdx.x;
    const int wave = tid >> 6;
    const int lane = tid & 63;
    const int mr   = lane & 15;
    const int lq   = lane >> 4;
    const int wr   = wave >> 2;     // 0..1 (M half)
    const int wc   = wave & 3;      // 0..3 (64-col f slice)

    // XCD swizzle: nwg = 736 = 8*92 exactly -> simple bijective form
    const int L   = (blockIdx.x & 7) * (NWG / 8) + (blockIdx.x >> 3);
    const int img = L / BPI;
    const int jb  = L - img * BPI;
    const int m0i = jb * BM;                         // within-image m base
    const int oh_first = m0i / OHW;
    const int ih0 = (oh_first < H_IN - 6) ? oh_first : (H_IN - 6); // rows ih0..ih0+5

    const unsigned short* ximg = xq + (size_t)img * (H_IN * ROW_SHORTS);

    // ---- stage 6 x rows once: LDS(r,w,cc) = x[ih0+r][w][cc ^ (w&7)] ----
    for (int r = 0; r < 6; ++r) {
        const unsigned short* xrow = ximg + (size_t)(ih0 + r) * ROW_SHORTS;
        unsigned short* lrow = Xlds + r * ROW_SHORTS;
        for (int i = wave; i < 14; i += 8) {         // 14 chunk-issues per row
            int c  = i * 64 + lane;                  // chunk id 0..895
            int w  = c >> 4;
            int cc = c & 15;
            async_copy16(xrow + w * C_IN + ((cc ^ (w & 7)) << 3),
                         lrow + i * 512);
        }
    }

    // ---- B fragment pointers (L2-hot 576 KB) ----
    const unsigned short* b_base = wpf + (size_t)(wc * 4) * 512 + lane * 8;
    bf16x8 s0[4], s1[4], s2[4];                      // 3-set rotation, 2 ahead

#define LOADB(SET, G)                                                         \
    {                                                                         \
        SET[0] = *reinterpret_cast<const bf16x8*>(b_base + (G) * 8192);       \
        SET[1] = *reinterpret_cast<const bf16x8*>(b_base + (G) * 8192 + 512); \
        SET[2] = *reinterpret_cast<const bf16x8*>(b_base + (G) * 8192 + 1024);\
        SET[3] = *reinterpret_cast<const bf16x8*>(b_base + (G) * 8192 + 1536);\
    }

    LOADB(s0, 0)
    LOADB(s1, 1)

    // ---- per-lane A geometry: 4 mi rows -> (oh,ow) -> LDS bases ----
    int arowbase[4];          // ((oh-ih0)*56 + ow)*128, shorts
    int e0[4], e1[4], e2[4];  // lq ^ ((ow+kw)&7) for kw = 0,1,2
#pragma unroll
    for (int mi = 0; mi < 4; ++mi) {
        int mloc = m0i + wr * 64 + mi * 16 + mr;
        if (mloc > RPI - 1) mloc = RPI - 1;          // tail block clamp
        int oh = mloc / OHW;
        int ow = mloc - oh * OHW;
        arowbase[mi] = ((oh - ih0) * W_IN + ow) * C_IN;
        e0[mi] = lq ^ (ow & 7);
        e1[mi] = lq ^ ((ow + 1) & 7);
        e2[mi] = lq ^ ((ow + 2) & 7);
    }

    f32x4 acc[4][4];
#pragma unroll
    for (int i = 0; i < 4; ++i)
#pragma unroll
        for (int j = 0; j < 4; ++j) acc[i][j] = (f32x4)(0.0f);

    __syncthreads();                                 // the ONLY barrier

    // ---- 36 barrier-free steps: g = kk*4 + ks ----
#define STEP(G, USE, LOAD)                                                    \
    {                                                                         \
        constexpr int kk_ = (G) >> 2, ks_ = (G) & 3;                          \
        constexpr int kh_ = kk_ / 3, kw_ = kk_ % 3;                           \
        constexpr int tap_ = (kh_ * W_IN + kw_) * C_IN;                       \
        if ((G) < 34) LOADB(LOAD, (G) + 2)                                    \
        const int* ep_ = (kw_ == 0) ? e0 : (kw_ == 1) ? e1 : e2;              \
        bf16x8 af_[4];                                                        \
        _Pragma("unroll")                                                     \
        for (int mi = 0; mi < 4; ++mi) {                                      \
            int cidx = ep_[mi] ^ (ks_ << 2);                                  \
            af_[mi] = *reinterpret_cast<const bf16x8*>(                       \
                Xlds + arowbase[mi] + tap_ + (cidx << 3));                    \
        }                                                                     \
        _Pragma("unroll")                                                     \
        for (int mi = 0; mi < 4; ++mi)                                        \
            _Pragma("unroll")                                                 \
            for (int ni = 0; ni < 4; ++ni)                                    \
                acc[mi][ni] = __builtin_amdgcn_mfma_f32_16x16x32_bf16(        \
                    af_[mi], USE[ni], acc[mi][ni], 0, 0, 0);                  \
    }
#define TRIPLE(G) STEP(G, s0, s2) STEP((G) + 1, s1, s0) STEP((G) + 2, s2, s1)

    TRIPLE(0)  TRIPLE(3)  TRIPLE(6)  TRIPLE(9)
    TRIPLE(12) TRIPLE(15) TRIPLE(18) TRIPLE(21)
    TRIPLE(24) TRIPLE(27) TRIPLE(30) TRIPLE(33)
#undef TRIPLE
#undef STEP
#undef LOADB

    // ---- epilogue: quantize, bias, ReLU (guard tail block rows) ----
    const int fcol0 = wc * 64 + mr;
    const size_t obase = (size_t)img * RPI;
#pragma unroll
    for (int mi = 0; mi < 4; ++mi) {
#pragma unroll
        for (int rr = 0; rr < 4; ++rr) {
            const int m_img = m0i + wr * 64 + mi * 16 + lq * 4 + rr;
            if (m_img < RPI) {
                const float* brow = bias + (size_t)m_img * F_OUT;
                float* orow = out + (obase + m_img) * F_OUT;
#pragma unroll
                for (int ni = 0; ni < 4; ++ni) {
                    float v = acc[mi][ni][rr];
                    float t = rintf(v * 256.0f);
                    t = fminf(fmaxf(t, -256.0f), 256.0f);
                    float o = t * 0.00390625f + brow[fcol0 + ni * 16];
                    orow[fcol0 + ni * 16] = fmaxf(o, 0.0f);
                }
            }
        }
    }
}

extern "C" void kernel_launch(void* const* d_in, const int* in_sizes, int n_in,
                              void* d_out, int out_size, void* d_ws, size_t ws_size,
                              hipStream_t stream) {
    (void)in_sizes; (void)n_in; (void)out_size;
    const float* x    = (const float*)d_in[0];
    const float* w    = (const float*)d_in[1];
    const float* bias = (const float*)d_in[2];
    float* out        = (float*)d_out;

    const size_t x_elems = (size_t)N_IMG * H_IN * W_IN * C_IN;
    const size_t w_elems = (size_t)9 * F_OUT * C_IN;
    const size_t xq_bytes = x_elems * sizeof(unsigned short);  // 16B-aligned
    const size_t need = xq_bytes + w_elems * sizeof(unsigned short);
    if (ws_size < need) return;

    unsigned short* xq  = (unsigned short*)d_ws;
    unsigned short* wpf = (unsigned short*)((char*)d_ws + xq_bytes);

    quant_x_kernel<<<(int)(x_elems / (256 * 4)), 256, 0, stream>>>(x, xq);
    quant_w_kernel<<<(int)(w_elems / 256), 256, 0, stream>>>(w, wpf);
    conv_kernel<<<NWG, 512, 0, stream>>>(xq, wpf, bias, out);
}

// Round 12
// 93.060 us; speedup vs baseline: 1.0242x; 1.0242x over previous
//
#include <hip/hip_runtime.h>
#include <hip/hip_bf16.h>
#include <stdint.h>
#include <stddef.h>

// ---------------------------------------------------------------------------
// MyConv2D fixed-point conv (Width=8), valid 3x3, NHWC, + bias + ReLU.
// R12: R9 skeleton (best verified: conv 70 us) with BK=128 (one full tap per
// K-tile) -> 9 tiles instead of 18: halves the per-tile vmcnt(0) drain
// events that keep MfmaUtil at 31%. A-only LDS double-buffer 64 KB
// (2 blocks/CU = 128 KB <= 160), global_load_lds w16, XOR swizzle (16
// slots/row, XOR low 3 bits — same proven 0-conflict class as R2-R9).
// B direct global->VGPR fragment-order (L2-hot), two 8-frag sets (P=ks01,
// Q=ks23) each loaded ~1 compute-phase ahead. XCD-chunked block swizzle.
// Exactness: quantized values a/256, |a|<=256 (bf16-exact); partial sums are
// integer multiples of 2^-16 << 2^24 -> fp32 MFMA accumulation exact.
// ---------------------------------------------------------------------------

typedef float  f32x4  __attribute__((ext_vector_type(4)));
typedef short  bf16x8 __attribute__((ext_vector_type(8)));

#define N_IMG 32
#define H_IN 56
#define W_IN 56
#define C_IN 128
#define F_OUT 256
#define OHW 54
#define M_TOTAL (N_IMG * OHW * OHW)   // 93312 = 729 * 128
#define BM 128
#define BN 128
#define TILE_SHORTS (BM * C_IN)        // 16384 shorts = 32 KB per buffer

__device__ __forceinline__ unsigned short quant_to_bf16(float x) {
    float a = rintf(x * 256.0f);                 // half-to-even == jnp.round
    a = fminf(fmaxf(a, -256.0f), 256.0f);
    float q = a * 0.00390625f;                   // exact in bf16
    union { float f; unsigned int u; } cv; cv.f = q;
    return (unsigned short)(cv.u >> 16);
}

__device__ __forceinline__ void async_copy16(const unsigned short* g, unsigned short* l) {
    __builtin_amdgcn_global_load_lds(
        (const __attribute__((address_space(1))) unsigned int*)g,
        (__attribute__((address_space(3))) unsigned int*)l, 16, 0, 0);
}

__global__ __launch_bounds__(256) void quant_x_kernel(
        const float* __restrict__ x, unsigned short* __restrict__ xq) {
    int i = (blockIdx.x * 256 + threadIdx.x) * 4;
    float4 v = *reinterpret_cast<const float4*>(x + i);
    ushort4 o;
    o.x = quant_to_bf16(v.x);
    o.y = quant_to_bf16(v.y);
    o.z = quant_to_bf16(v.z);
    o.w = quant_to_bf16(v.w);
    *reinterpret_cast<ushort4*>(xq + i) = o;
}

// w (3,3,128,256) -> wpf in MFMA-B fragment order (same as R9):
//   idx = ((((kk*2 + hf)*2 + ks)*16 + g)*64 + l)*8 + j
//   element: f = g*16 + (l&15); c = hf*64 + ks*32 + (l>>4)*8 + j; tap kk
// For BK=128: frag(kk, ks'=0..3, ni) = wpf + kk*32768 + ks'*8192 + ni*512.
__global__ __launch_bounds__(256) void quant_w_kernel(
        const float* __restrict__ w, unsigned short* __restrict__ wpf) {
    int idx = blockIdx.x * 256 + threadIdx.x;     // 294912 total
    int j  = idx & 7;
    int l  = (idx >> 3) & 63;
    int g  = (idx >> 9) & 15;
    int ks = (idx >> 13) & 1;
    int hf = (idx >> 14) & 1;
    int kk = idx >> 15;
    int f  = g * 16 + (l & 15);
    int c  = hf * 64 + ks * 32 + (l >> 4) * 8 + j;
    wpf[idx] = quant_to_bf16(w[(kk * C_IN + c) * F_OUT + f]);
}

__global__ __launch_bounds__(256, 2) void conv_kernel(
        const unsigned short* __restrict__ xq,   // [32][56][56][128] bf16
        const unsigned short* __restrict__ wpf,  // fragment-ordered B
        const float* __restrict__ bias,          // [54][54][256]
        float* __restrict__ out)                 // [93312][256]
{
    __shared__ __attribute__((aligned(16))) unsigned short Alds[2][TILE_SHORTS]; // 64 KB

    const int tid  = threadIdx.x;
    const int wave = tid >> 6;
    const int lane = tid & 63;

    // bijective XCD-chunked swizzle: nwg=1458 = 8*182 + 2 (m204)
    int L;
    {
        int bid = blockIdx.x;
        int xcd = bid & 7, idx = bid >> 3;
        L = (xcd < 2) ? xcd * 183 + idx : 366 + (xcd - 2) * 182 + idx;
    }
    const int mb = L >> 1;          // consecutive L pairs share identical A
    const int nb = L & 1;
    const int m0 = mb * BM;
    const int wr = wave >> 1;       // 0..1
    const int wc = wave & 1;        // 0..1

    // ---- A staging geometry (BK=128): chunk c = 256r + tid, r=0..7 ----
    // row = c>>4 = 16r + (tid>>4); stored slot s = tid&15;
    // source chunk g = s ^ (row&7) = (tid&15) ^ ((tid>>4)&7)  (16r == 0 mod 8)
    const int sw   = (tid & 15) ^ ((tid >> 4) & 7);
    const int dstc = tid & ~63;                   // wave-uniform lane-block

    const unsigned short* a_base[8];
#pragma unroll
    for (int r = 0; r < 8; ++r) {
        int m = m0 + 16 * r + (tid >> 4);
        int n_img = m / (OHW * OHW);
        int rem   = m % (OHW * OHW);
        int oh = rem / OHW, ow = rem % OHW;
        a_base[r] = xq + (size_t)((n_img * H_IN + oh) * W_IN + ow) * C_IN + sw * 8;
    }

    // stage tap kk into buffer Ab: 8 gloads/thread (16B each), 32 KB total
    auto stageA = [&](int kk, unsigned short* Ab) {
        int kh = (kk * 43) >> 7, kw = kk - 3 * kh;   // kk/3, kk%3 for kk<=8
        int aoff = (kh * W_IN + kw) * C_IN;
#pragma unroll
        for (int r = 0; r < 8; ++r)
            async_copy16(a_base[r] + aoff, Ab + (256 * r + dstc) * 8);
    };

    // ---- B fragment loads: two 8-frag sets, P = ks'0..1, Q = ks'2..3 ----
    const unsigned short* b_base = wpf + (size_t)(nb * 8 + wc * 4) * 512 + lane * 8;

    bf16x8 bP[4][2], bQ[4][2];     // [ni][ks-within-half]
    auto loadB_P = [&](int kk) {   // ks' 0,1 of tap kk
#pragma unroll
        for (int ni = 0; ni < 4; ++ni)
#pragma unroll
            for (int h = 0; h < 2; ++h)
                bP[ni][h] = *reinterpret_cast<const bf16x8*>(
                    b_base + kk * 32768 + h * 8192 + ni * 512);
    };
    auto loadB_Q = [&](int kk) {   // ks' 2,3 of tap kk
#pragma unroll
        for (int ni = 0; ni < 4; ++ni)
#pragma unroll
            for (int h = 0; h < 2; ++h)
                bQ[ni][h] = *reinterpret_cast<const bf16x8*>(
                    b_base + kk * 32768 + (2 + h) * 8192 + ni * 512);
    };

    // ---- fragment read geometry (A from LDS, swizzled 16 slots/row) ----
    const int mr = lane & 15;
    const int lq = lane >> 4;

    f32x4 acc[4][4];
#pragma unroll
    for (int i = 0; i < 4; ++i)
#pragma unroll
        for (int j = 0; j < 4; ++j) acc[i][j] = (f32x4)(0.0f);

    auto computeP = [&](const unsigned short* Ab) {   // ks' 0,1 with bP
#pragma unroll
        for (int h = 0; h < 2; ++h) {
            const int ch = (((h * 4 + lq) ^ (mr & 7)) * 8);
            bf16x8 af[4];
#pragma unroll
            for (int mi = 0; mi < 4; ++mi)
                af[mi] = *reinterpret_cast<const bf16x8*>(
                    Ab + (wr * 64 + mi * 16 + mr) * C_IN + ch);
#pragma unroll
            for (int mi = 0; mi < 4; ++mi)
#pragma unroll
                for (int ni = 0; ni < 4; ++ni)
                    acc[mi][ni] = __builtin_amdgcn_mfma_f32_16x16x32_bf16(
                        af[mi], bP[ni][h], acc[mi][ni], 0, 0, 0);
        }
    };
    auto computeQ = [&](const unsigned short* Ab) {   // ks' 2,3 with bQ
#pragma unroll
        for (int h = 0; h < 2; ++h) {
            const int ch = ((((2 + h) * 4 + lq) ^ (mr & 7)) * 8);
            bf16x8 af[4];
#pragma unroll
            for (int mi = 0; mi < 4; ++mi)
                af[mi] = *reinterpret_cast<const bf16x8*>(
                    Ab + (wr * 64 + mi * 16 + mr) * C_IN + ch);
#pragma unroll
            for (int mi = 0; mi < 4; ++mi)
#pragma unroll
                for (int ni = 0; ni < 4; ++ni)
                    acc[mi][ni] = __builtin_amdgcn_mfma_f32_16x16x32_bf16(
                        af[mi], bQ[ni][h], acc[mi][ni], 0, 0, 0);
        }
    };

    // ---- prologue: tap 0 A + P(0); drain ----
    stageA(0, Alds[0]);
    loadB_P(0);
    __syncthreads();

    // ---- main loop over taps 0..7 (stage 1..8), tail tap 8 ----
#pragma unroll 1
    for (int t = 0; t < 8; ++t) {
        unsigned short* cur = Alds[t & 1];
        stageA(t + 1, Alds[(t + 1) & 1]);  // HBM: full tile of latency cover
        loadB_Q(t);                        // L2: one compute-phase ahead
        computeP(cur);
        loadB_P(t + 1);                    // L2: used after barrier
        computeQ(cur);
        __syncthreads();                   // implicit vmcnt(0): t+1 landed
    }
    {
        unsigned short* cur = Alds[0];     // tap 8 -> buffer (8&1)=0
        loadB_Q(8);
        computeP(cur);
        computeQ(cur);
    }

    // ---- epilogue: quantize, bias, ReLU ----
    const int fcol0 = nb * BN + wc * 64 + mr;
#pragma unroll
    for (int mi = 0; mi < 4; ++mi) {
#pragma unroll
        for (int rr = 0; rr < 4; ++rr) {
            const int m = m0 + wr * 64 + mi * 16 + lq * 4 + rr;
            const float* brow = bias + (size_t)(m % (OHW * OHW)) * F_OUT;
            float* orow = out + (size_t)m * F_OUT;
#pragma unroll
            for (int ni = 0; ni < 4; ++ni) {
                float v = acc[mi][ni][rr];
                float t = rintf(v * 256.0f);
                t = fminf(fmaxf(t, -256.0f), 256.0f);
                float o = t * 0.00390625f + brow[fcol0 + ni * 16];
                orow[fcol0 + ni * 16] = fmaxf(o, 0.0f);
            }
        }
    }
}

extern "C" void kernel_launch(void* const* d_in, const int* in_sizes, int n_in,
                              void* d_out, int out_size, void* d_ws, size_t ws_size,
                              hipStream_t stream) {
    (void)in_sizes; (void)n_in; (void)out_size;
    const float* x    = (const float*)d_in[0];
    const float* w    = (const float*)d_in[1];
    const float* bias = (const float*)d_in[2];
    float* out        = (float*)d_out;

    const size_t x_elems = (size_t)N_IMG * H_IN * W_IN * C_IN;
    const size_t w_elems = (size_t)9 * F_OUT * C_IN;
    const size_t xq_bytes = x_elems * sizeof(unsigned short);  // 16B-aligned
    const size_t need = xq_bytes + w_elems * sizeof(unsigned short);
    if (ws_size < need) return;

    unsigned short* xq  = (unsigned short*)d_ws;
    unsigned short* wpf = (unsigned short*)((char*)d_ws + xq_bytes);

    quant_x_kernel<<<(int)(x_elems / (256 * 4)), 256, 0, stream>>>(x, xq);
    quant_w_kernel<<<(int)(w_elems / 256), 256, 0, stream>>>(w, wpf);
    conv_kernel<<<(M_TOTAL / BM) * 2, 256, 0, stream>>>(xq, wpf, bias, out);
}